// Round 3
// baseline (4587.225 us; speedup 1.0000x reference)
//
#include <hip/hip_runtime.h>
#include <hip/hip_bf16.h>

// ---------------------------------------------------------------------------
// Model: x:(256,1,96) -> 24-layer biLSTM (scan over batch axis! N=96 rows are
// independent chains, T=256 steps) -> slice n in [48,96) -> 24-layer biLSTM
// (N=48) -> z=h2+x1 -> fc1(1536->1000,relu) -> fc2(1000->48) -> FP32 out.
// (Round-2 fix: output dtype is float32, NOT bf16 — the absmax-11.125
//  signature was bf16 pairs packed into a float buffer.)
// Latency-bound: 48 sequential layer stages x 256 sequential steps.
// Mapping: one wave per chain; lane 4j+g owns gate g of row j; h broadcast via
// v_readlane into SGPRs; i/f/g/o gather via __shfl; x-projection
// software-pipelined one step ahead.
// ---------------------------------------------------------------------------

__device__ __forceinline__ float fast_sigmoid(float x) {
  float e = __builtin_amdgcn_exp2f(-1.44269504f * x);
  return __builtin_amdgcn_rcpf(1.0f + e);
}
__device__ __forceinline__ float fast_tanh(float x) {
  float e = __builtin_amdgcn_exp2f(2.88539008f * x);
  return 1.0f - 2.0f * __builtin_amdgcn_rcpf(1.0f + e);
}

// Broadcast lane ((lane & ~3) | sel)'s value of v to all lanes of the quad.
__device__ __forceinline__ float quad_get(float v, int sel) {
  const int src = (threadIdx.x & ~3) | sel;
  return __shfl(v, src, 64);
}

// One wave (64 threads) per (direction, chain). IN_SZ in {1,32}. N chains/dir.
// xin index: t*t_stride + (n+n_off)*IN_SZ + k ; xout: (t*N+n)*32 + d*16 + j.
template <int IN_SZ, int N>
__global__ __launch_bounds__(64) void lstm_layer(
    const float* __restrict__ xin, float* __restrict__ xout,
    const float* __restrict__ Wih, const float* __restrict__ Whh,
    const float* __restrict__ bih, const float* __restrict__ bhh,
    int t_stride, int n_off) {
  const int lane = threadIdx.x;
  const int d = blockIdx.x / N;  // 0 fwd, 1 bwd
  const int n = blockIdx.x % N;
  const int j = lane >> 2;
  const int g = lane & 3;
  const int r = g * 16 + j;  // gate row: i=0..15, f=16..31, g=32..47, o=48..63

  float whh[16];
#pragma unroll
  for (int k = 0; k < 16; ++k) whh[k] = Whh[(d * 64 + r) * 16 + k];
  float wih[IN_SZ];
#pragma unroll
  for (int k = 0; k < IN_SZ; ++k) wih[k] = Wih[(d * 64 + r) * IN_SZ + k];
  const float bias = bih[d * 64 + r] + bhh[d * 64 + r];

  float hs[16];  // uniform (SGPR) copy of h
#pragma unroll
  for (int k = 0; k < 16; ++k) hs[k] = 0.0f;
  float c = 0.0f;

  const int dt = d ? -1 : 1;
  int t = d ? 255 : 0;

  // prologue: x-projection for first step
  float xacc;
  {
    const float* p = xin + (size_t)t * t_stride + (size_t)(n + n_off) * IN_SZ;
    float a0 = bias, a1 = 0.f, a2 = 0.f, a3 = 0.f;
#pragma unroll
    for (int k = 0; k < IN_SZ; k += 4) {
      a0 = fmaf(wih[k], p[k], a0);
      if (k + 1 < IN_SZ) a1 = fmaf(wih[k + 1], p[k + 1], a1);
      if (k + 2 < IN_SZ) a2 = fmaf(wih[k + 2], p[k + 2], a2);
      if (k + 3 < IN_SZ) a3 = fmaf(wih[k + 3], p[k + 3], a3);
    }
    xacc = (a0 + a1) + (a2 + a3);
  }

  for (int tt = 0; tt < 256; ++tt) {
    // issue next-step x loads early (wave-uniform -> scalar loads); consumed
    // only at the bottom of the iteration, so latency hides under the h-chain.
    float xr[IN_SZ];
    const int tn = t + dt;
    if (tt < 255) {
      const float* p =
          xin + (size_t)tn * t_stride + (size_t)(n + n_off) * IN_SZ;
#pragma unroll
      for (int k = 0; k < IN_SZ; ++k) xr[k] = p[k];
    }

    // gate value for this lane: bias + Wih.x (precomputed) + Whh.h
    float a0 = xacc, a1 = 0.f, a2 = 0.f, a3 = 0.f;
#pragma unroll
    for (int k = 0; k < 16; k += 4) {
      a0 = fmaf(whh[k + 0], hs[k + 0], a0);
      a1 = fmaf(whh[k + 1], hs[k + 1], a1);
      a2 = fmaf(whh[k + 2], hs[k + 2], a2);
      a3 = fmaf(whh[k + 3], hs[k + 3], a3);
    }
    const float gv = (a0 + a1) + (a2 + a3);

    // gather the quad's 4 gate values into every lane
    const float iv = quad_get(gv, 0);
    const float fv = quad_get(gv, 1);
    const float gg = quad_get(gv, 2);
    const float ov = quad_get(gv, 3);

    const float si = fast_sigmoid(iv);
    const float sf = fast_sigmoid(fv);
    const float tg = fast_tanh(gg);
    const float so = fast_sigmoid(ov);
    c = fmaf(sf, c, si * tg);  // all 4 lanes of quad j compute row j redundantly
    const float h = so * fast_tanh(c);

    if (g == 0) xout[((size_t)t * N + n) * 32 + d * 16 + j] = h;

    // broadcast h back to uniform registers for next step's matvec
    const int hb = __float_as_int(h);
#pragma unroll
    for (int k = 0; k < 16; ++k)
      hs[k] = __int_as_float(__builtin_amdgcn_readlane(hb, 4 * k));

    // next step's x-projection (loads already in flight)
    if (tt < 255) {
      float b0 = bias, b1 = 0.f, b2 = 0.f, b3 = 0.f;
#pragma unroll
      for (int k = 0; k < IN_SZ; k += 4) {
        b0 = fmaf(wih[k], xr[k], b0);
        if (k + 1 < IN_SZ) b1 = fmaf(wih[k + 1], xr[k + 1], b1);
        if (k + 2 < IN_SZ) b2 = fmaf(wih[k + 2], xr[k + 2], b2);
        if (k + 3 < IN_SZ) b3 = fmaf(wih[k + 3], xr[k + 3], b3);
      }
      xacc = (b0 + b1) + (b2 + b3);
    }
    t = tn;
  }
}

// fc1: y1[b,m] = relu( sum_k (h2[b,k] + x1[b,k]) * w1[m,k] + b1[m] )
// M=256(b), Nout=1000(m), K=1536. 64x64 tiles, 256 threads, 4x4 per thread.
__global__ __launch_bounds__(256) void fc1_kernel(
    const float* __restrict__ h2,   // (256,48,32) flat = (256,1536)
    const float* __restrict__ x1b,  // (256,96,32); use n>=48 -> +1536 offset
    const float* __restrict__ w1, const float* __restrict__ b1,
    float* __restrict__ y1) {
  __shared__ float Zs[64][17];
  __shared__ float Ws[64][17];
  const int tid = threadIdx.x;
  const int m0 = blockIdx.x * 64;
  const int b0 = blockIdx.y * 64;
  const int rr = tid >> 2;       // 0..63
  const int c4 = (tid & 3) * 4;  // 0,4,8,12
  const int tx = tid & 15, ty = tid >> 4;

  float acc[4][4];
#pragma unroll
  for (int i = 0; i < 4; ++i)
#pragma unroll
    for (int jj = 0; jj < 4; ++jj) acc[i][jj] = 0.f;

  const bool wvalid = (m0 + rr) < 1000;

  for (int k0 = 0; k0 < 1536; k0 += 16) {
    const int k = k0 + c4;
    const float4 za =
        *reinterpret_cast<const float4*>(h2 + (size_t)(b0 + rr) * 1536 + k);
    const float4 zb = *reinterpret_cast<const float4*>(
        x1b + (size_t)(b0 + rr) * 3072 + 1536 + k);
    Zs[rr][c4 + 0] = za.x + zb.x;
    Zs[rr][c4 + 1] = za.y + zb.y;
    Zs[rr][c4 + 2] = za.z + zb.z;
    Zs[rr][c4 + 3] = za.w + zb.w;
    float4 wv = make_float4(0.f, 0.f, 0.f, 0.f);
    if (wvalid)
      wv = *reinterpret_cast<const float4*>(w1 + (size_t)(m0 + rr) * 1536 + k);
    Ws[rr][c4 + 0] = wv.x;
    Ws[rr][c4 + 1] = wv.y;
    Ws[rr][c4 + 2] = wv.z;
    Ws[rr][c4 + 3] = wv.w;
    __syncthreads();
#pragma unroll
    for (int kk = 0; kk < 16; ++kk) {
      float av[4], bv[4];
#pragma unroll
      for (int i = 0; i < 4; ++i) av[i] = Zs[ty * 4 + i][kk];
#pragma unroll
      for (int i = 0; i < 4; ++i) bv[i] = Ws[tx * 4 + i][kk];
#pragma unroll
      for (int i = 0; i < 4; ++i)
#pragma unroll
        for (int jj = 0; jj < 4; ++jj)
          acc[i][jj] = fmaf(av[i], bv[jj], acc[i][jj]);
    }
    __syncthreads();
  }
#pragma unroll
  for (int i = 0; i < 4; ++i) {
    const int b = b0 + ty * 4 + i;
#pragma unroll
    for (int jj = 0; jj < 4; ++jj) {
      const int m = m0 + tx * 4 + jj;
      if (m < 1000) {
        float v = acc[i][jj] + b1[m];
        y1[(size_t)b * 1000 + m] = v > 0.f ? v : 0.f;
      }
    }
  }
}

// fc2: out[b,p] = sum_m y1[b,m]*w2[p,m] + b2[p], p<48; FP32 store.
__global__ __launch_bounds__(64) void fc2_kernel(
    const float* __restrict__ y1, const float* __restrict__ w2,
    const float* __restrict__ b2, float* __restrict__ out) {
  __shared__ float ys[1000];
  const int b = blockIdx.x;
  for (int k = threadIdx.x; k < 1000; k += 64) ys[k] = y1[(size_t)b * 1000 + k];
  __syncthreads();
  const int p = threadIdx.x;
  if (p < 48) {
    float a0 = b2[p], a1 = 0.f, a2 = 0.f, a3 = 0.f;
    const float* wr = w2 + (size_t)p * 1000;
    for (int k = 0; k < 1000; k += 4) {
      const float4 wv = *reinterpret_cast<const float4*>(wr + k);
      a0 = fmaf(ys[k + 0], wv.x, a0);
      a1 = fmaf(ys[k + 1], wv.y, a1);
      a2 = fmaf(ys[k + 2], wv.z, a2);
      a3 = fmaf(ys[k + 3], wv.w, a3);
    }
    out[(size_t)b * 48 + p] = (a0 + a1) + (a2 + a3);
  }
}

extern "C" void kernel_launch(void* const* d_in, const int* in_sizes, int n_in,
                              void* d_out, int out_size, void* d_ws,
                              size_t ws_size, hipStream_t stream) {
  const float* x = (const float*)d_in[0];
  const float* W_ih0_1 = (const float*)d_in[1];
  const float* W_ih_1 = (const float*)d_in[2];
  const float* W_hh_1 = (const float*)d_in[3];
  const float* b_ih_1 = (const float*)d_in[4];
  const float* b_hh_1 = (const float*)d_in[5];
  const float* W_ih_2 = (const float*)d_in[6];
  const float* W_hh_2 = (const float*)d_in[7];
  const float* b_ih_2 = (const float*)d_in[8];
  const float* b_hh_2 = (const float*)d_in[9];
  const float* fc1_w = (const float*)d_in[10];
  const float* fc1_b = (const float*)d_in[11];
  const float* fc2_w = (const float*)d_in[12];
  const float* fc2_b = (const float*)d_in[13];

  float* ws = (float*)d_ws;
  float* buf0 = ws;               // 786432 floats (256*96*32)
  float* buf1 = ws + 786432;      // 786432 floats — stack1 final (x1 source)
  float* y1 = ws + 2 * 786432;    // 256000 floats
  float* q0 = buf0;               // stack2 ping/pong alias buf0 (safe)
  float* q1 = buf0 + 393216;

  // ---- stack 1 (N=96 chains/dir, input t-stride 96; layer0 in_sz=1) ----
  lstm_layer<1, 96><<<192, 64, 0, stream>>>(x, buf0, W_ih0_1, W_hh_1, b_ih_1,
                                            b_hh_1, 96, 0);
  for (int l = 1; l < 24; ++l) {
    const float* in = (l & 1) ? buf0 : buf1;
    float* outb = (l & 1) ? buf1 : buf0;
    lstm_layer<32, 96><<<192, 64, 0, stream>>>(
        in, outb, W_ih_1 + (size_t)(l - 1) * 4096, W_hh_1 + (size_t)l * 2048,
        b_ih_1 + l * 128, b_hh_1 + l * 128, 3072, 0);
  }
  // ---- stack 2 (N=48; layer0 reads stack1-final with n_off=48) ----
  lstm_layer<32, 48><<<96, 64, 0, stream>>>(buf1, q0, W_ih_2, W_hh_2, b_ih_2,
                                            b_hh_2, 3072, 48);
  for (int l = 1; l < 24; ++l) {
    const float* in = (l & 1) ? q0 : q1;
    float* outb = (l & 1) ? q1 : q0;
    lstm_layer<32, 48><<<96, 64, 0, stream>>>(
        in, outb, W_ih_2 + (size_t)l * 4096, W_hh_2 + (size_t)l * 2048,
        b_ih_2 + l * 128, b_hh_2 + l * 128, 1536, 0);
  }
  // ---- FC head ----
  fc1_kernel<<<dim3(16, 4), 256, 0, stream>>>(q1, buf1, fc1_w, fc1_b, y1);
  fc2_kernel<<<256, 64, 0, stream>>>(y1, fc2_w, fc2_b, (float*)d_out);
}

// Round 4
// 2640.490 us; speedup vs baseline: 1.7373x; 1.7373x over previous
//
#include <hip/hip_runtime.h>

// ---------------------------------------------------------------------------
// Model: x:(256,1,96) -> 24-layer biLSTM (scan over batch axis: N=96 rows are
// independent chains, T=256 steps) -> slice n in [48,96) -> 24-layer biLSTM
// (N=48) -> z=h2+x1 -> fc1(1536->1000,relu) -> fc2(1000->48) -> FP32 out.
//
// Round-4 restructure (latency regime: ~1 wave/CU, every issue slot is on the
// critical path):
//  - phase 1: all 4 waves of the block compute xg[t][r]=bias+Wih.x[t] into
//    64KB LDS (parallel over t) -> x-projection removed from the recurrence.
//  - phase 2: wave 0 runs the 256-step recurrence; per-step chain is only
//    16-FMA matvec + 1 exp + 1 rcp (per-lane pre-gather activation) + 4 DPP
//    quad-broadcasts + c/tanh chain + 16 readlanes. LDS xg read prefetched
//    one step ahead.
//  - fc1: k-major LDS (Zs[16][68]) -> ds_read_b128 inner loop (was 2.65M
//    bank-conflict cycles from stride-17 scalar reads).
// ---------------------------------------------------------------------------

template <int SEL>
__device__ __forceinline__ float quad_bcast(float v) {
  // quad_perm broadcasting lane SEL of each quad (verified equivalent to
  // __shfl by the round-1 <-> round-2 bisect).
  return __int_as_float(__builtin_amdgcn_update_dpp(
      0, __float_as_int(v), SEL * 0x55, 0xF, 0xF, true));
}

// One block (256 threads) per (direction, chain). Wave 0 does the recurrence.
// xin index: t*t_stride + (n+n_off)*IN_SZ + k ; xout: (t*N+n)*32 + d*16 + j.
template <int IN_SZ, int N>
__global__ __launch_bounds__(256) void lstm_layer(
    const float* __restrict__ xin, float* __restrict__ xout,
    const float* __restrict__ Wih, const float* __restrict__ Whh,
    const float* __restrict__ bih, const float* __restrict__ bhh,
    int t_stride, int n_off) {
  __shared__ float xg[256 * 64];  // 64 KB: xg[t][r]

  const int tid = threadIdx.x;
  const int lane = tid & 63;
  const int w = tid >> 6;
  const int d = blockIdx.x / N;  // 0 fwd, 1 bwd
  const int n = blockIdx.x % N;

  // ---- phase 1: xg[t][r] = bih[r]+bhh[r] + Wih[d*64+r,:] . x[t,n,:] ----
  {
    const int r = lane;
    const float bias = bih[d * 64 + r] + bhh[d * 64 + r];
    if constexpr (IN_SZ == 1) {
      const float wih0 = Wih[d * 64 + r];
      for (int ti = 0; ti < 64; ++ti) {
        const int t = w * 64 + ti;
        const float xv = xin[(size_t)t * t_stride + (n + n_off)];
        xg[t * 64 + r] = fmaf(wih0, xv, bias);
      }
    } else {
      float wih[IN_SZ];
#pragma unroll
      for (int k = 0; k < IN_SZ; ++k)
        wih[k] = Wih[(size_t)(d * 64 + r) * IN_SZ + k];
      for (int ti = 0; ti < 64; ++ti) {
        const int t = w * 64 + ti;
        const float4* p4 = reinterpret_cast<const float4*>(
            xin + (size_t)t * t_stride + (size_t)(n + n_off) * IN_SZ);
        float a0 = bias, a1 = 0.f, a2 = 0.f, a3 = 0.f;
#pragma unroll
        for (int q = 0; q < IN_SZ / 4; ++q) {
          const float4 xv = p4[q];
          a0 = fmaf(wih[4 * q + 0], xv.x, a0);
          a1 = fmaf(wih[4 * q + 1], xv.y, a1);
          a2 = fmaf(wih[4 * q + 2], xv.z, a2);
          a3 = fmaf(wih[4 * q + 3], xv.w, a3);
        }
        xg[t * 64 + r] = (a0 + a1) + (a2 + a3);
      }
    }
  }
  __syncthreads();
  if (w != 0) return;  // waves 1-3 done

  // ---- phase 2: recurrence (wave 0 only) ----
  const int j = lane >> 2;
  const int g = lane & 3;
  const int r = g * 16 + j;  // gate row: i,f,g,o blocks of 16

  float whh[16];
#pragma unroll
  for (int k = 0; k < 16; ++k) whh[k] = Whh[(d * 64 + r) * 16 + k];

  // per-lane activation constants: sigmoid for g!=2, tanh for g==2
  //   e = exp2(s*x); v = m*rcp(1+e) + b
  const float s_ = (g == 2) ? 2.885390082f : -1.442695041f;
  const float m_ = (g == 2) ? -2.0f : 1.0f;
  const float b_ = (g == 2) ? 1.0f : 0.0f;

  float hs[16];  // uniform copy of h (SGPRs via readlane)
#pragma unroll
  for (int k = 0; k < 16; ++k) hs[k] = 0.f;
  float c = 0.f;

  const int dt = d ? -1 : 1;
  int t = d ? 255 : 0;
  float cur = xg[t * 64 + r];
  float* outp = xout + ((size_t)t * N + n) * 32 + d * 16 + j;
  const ptrdiff_t ostep = (ptrdiff_t)dt * N * 32;

  for (int tt = 0; tt < 256; ++tt) {
    // prefetch next step's xg (index wrapped; value unused on last iter)
    const int tn = (t + dt) & 255;
    const float nxt = xg[tn * 64 + r];

    // gate pre-activation: cur (bias + Wih.x) + Whh.h
    float a0 = cur, a1 = 0.f, a2 = 0.f, a3 = 0.f;
#pragma unroll
    for (int k = 0; k < 16; k += 4) {
      a0 = fmaf(whh[k + 0], hs[k + 0], a0);
      a1 = fmaf(whh[k + 1], hs[k + 1], a1);
      a2 = fmaf(whh[k + 2], hs[k + 2], a2);
      a3 = fmaf(whh[k + 3], hs[k + 3], a3);
    }
    const float gv = (a0 + a1) + (a2 + a3);

    // this lane's own activation, then quad gather of activated values
    const float e = __builtin_amdgcn_exp2f(s_ * gv);
    const float v = fmaf(m_, __builtin_amdgcn_rcpf(1.0f + e), b_);
    const float si = quad_bcast<0>(v);
    const float sf = quad_bcast<1>(v);
    const float tg = quad_bcast<2>(v);
    const float so = quad_bcast<3>(v);

    c = fmaf(sf, c, si * tg);  // redundant across the quad (free)
    const float e2 = __builtin_amdgcn_exp2f(2.885390082f * c);
    const float th = fmaf(-2.0f, __builtin_amdgcn_rcpf(1.0f + e2), 1.0f);
    const float h = so * th;

    if (g == 0) *outp = h;
    outp += ostep;

    const int hb = __float_as_int(h);
#pragma unroll
    for (int k = 0; k < 16; ++k)
      hs[k] = __int_as_float(__builtin_amdgcn_readlane(hb, 4 * k));

    cur = nxt;
    t += dt;
  }
}

// fc1: y1[b,m] = relu( sum_k (h2[b,k] + x1[b,k]) * w1[m,k] + b1[m] )
// 64x64 tiles, 256 threads, 4x4 per thread; k-major LDS for b128 reads.
__global__ __launch_bounds__(256) void fc1_kernel(
    const float* __restrict__ h2,   // (256,1536)
    const float* __restrict__ x1b,  // (256,3072); back half is x1
    const float* __restrict__ w1, const float* __restrict__ b1,
    float* __restrict__ y1) {
  __shared__ float Zs[16][68];  // [k within tile][row], pad 68 for b128 align
  __shared__ float Ws[16][68];
  const int tid = threadIdx.x;
  const int m0 = blockIdx.x * 64;
  const int b0 = blockIdx.y * 64;
  const int rr = tid >> 2;       // 0..63
  const int c4 = (tid & 3) * 4;  // 0,4,8,12
  const int tx = tid & 15, ty = tid >> 4;

  float acc[4][4];
#pragma unroll
  for (int i = 0; i < 4; ++i)
#pragma unroll
    for (int jj = 0; jj < 4; ++jj) acc[i][jj] = 0.f;

  const bool wvalid = (m0 + rr) < 1000;

  for (int k0 = 0; k0 < 1536; k0 += 16) {
    const int k = k0 + c4;
    const float4 za =
        *reinterpret_cast<const float4*>(h2 + (size_t)(b0 + rr) * 1536 + k);
    const float4 zb = *reinterpret_cast<const float4*>(
        x1b + (size_t)(b0 + rr) * 3072 + 1536 + k);
    Zs[c4 + 0][rr] = za.x + zb.x;
    Zs[c4 + 1][rr] = za.y + zb.y;
    Zs[c4 + 2][rr] = za.z + zb.z;
    Zs[c4 + 3][rr] = za.w + zb.w;
    float4 wv = make_float4(0.f, 0.f, 0.f, 0.f);
    if (wvalid)
      wv = *reinterpret_cast<const float4*>(w1 + (size_t)(m0 + rr) * 1536 + k);
    Ws[c4 + 0][rr] = wv.x;
    Ws[c4 + 1][rr] = wv.y;
    Ws[c4 + 2][rr] = wv.z;
    Ws[c4 + 3][rr] = wv.w;
    __syncthreads();
#pragma unroll
    for (int kk = 0; kk < 16; ++kk) {
      const float4 av = *reinterpret_cast<const float4*>(&Zs[kk][ty * 4]);
      const float4 bv = *reinterpret_cast<const float4*>(&Ws[kk][tx * 4]);
      const float a_[4] = {av.x, av.y, av.z, av.w};
      const float b_[4] = {bv.x, bv.y, bv.z, bv.w};
#pragma unroll
      for (int i = 0; i < 4; ++i)
#pragma unroll
        for (int jj = 0; jj < 4; ++jj)
          acc[i][jj] = fmaf(a_[i], b_[jj], acc[i][jj]);
    }
    __syncthreads();
  }
#pragma unroll
  for (int i = 0; i < 4; ++i) {
    const int b = b0 + ty * 4 + i;
#pragma unroll
    for (int jj = 0; jj < 4; ++jj) {
      const int m = m0 + tx * 4 + jj;
      if (m < 1000) {
        float v = acc[i][jj] + b1[m];
        y1[(size_t)b * 1000 + m] = v > 0.f ? v : 0.f;
      }
    }
  }
}

// fc2: out[b,p] = sum_m y1[b,m]*w2[p,m] + b2[p], p<48; FP32 store.
__global__ __launch_bounds__(64) void fc2_kernel(
    const float* __restrict__ y1, const float* __restrict__ w2,
    const float* __restrict__ b2, float* __restrict__ out) {
  __shared__ float ys[1000];
  const int b = blockIdx.x;
  for (int k = threadIdx.x; k < 1000; k += 64) ys[k] = y1[(size_t)b * 1000 + k];
  __syncthreads();
  const int p = threadIdx.x;
  if (p < 48) {
    float a0 = b2[p], a1 = 0.f, a2 = 0.f, a3 = 0.f;
    const float* wr = w2 + (size_t)p * 1000;
    for (int k = 0; k < 1000; k += 4) {
      const float4 wv = *reinterpret_cast<const float4*>(wr + k);
      a0 = fmaf(ys[k + 0], wv.x, a0);
      a1 = fmaf(ys[k + 1], wv.y, a1);
      a2 = fmaf(ys[k + 2], wv.z, a2);
      a3 = fmaf(ys[k + 3], wv.w, a3);
    }
    out[(size_t)b * 48 + p] = (a0 + a1) + (a2 + a3);
  }
}

extern "C" void kernel_launch(void* const* d_in, const int* in_sizes, int n_in,
                              void* d_out, int out_size, void* d_ws,
                              size_t ws_size, hipStream_t stream) {
  const float* x = (const float*)d_in[0];
  const float* W_ih0_1 = (const float*)d_in[1];
  const float* W_ih_1 = (const float*)d_in[2];
  const float* W_hh_1 = (const float*)d_in[3];
  const float* b_ih_1 = (const float*)d_in[4];
  const float* b_hh_1 = (const float*)d_in[5];
  const float* W_ih_2 = (const float*)d_in[6];
  const float* W_hh_2 = (const float*)d_in[7];
  const float* b_ih_2 = (const float*)d_in[8];
  const float* b_hh_2 = (const float*)d_in[9];
  const float* fc1_w = (const float*)d_in[10];
  const float* fc1_b = (const float*)d_in[11];
  const float* fc2_w = (const float*)d_in[12];
  const float* fc2_b = (const float*)d_in[13];

  float* ws = (float*)d_ws;
  float* buf0 = ws;             // 786432 floats (256*96*32)
  float* buf1 = ws + 786432;    // stack1 final (x1 source)
  float* y1 = ws + 2 * 786432;  // 256000 floats
  float* q0 = buf0;             // stack2 ping/pong alias buf0 (safe)
  float* q1 = buf0 + 393216;

  // ---- stack 1 (N=96 chains/dir; layer0 in_sz=1, t_stride=96) ----
  lstm_layer<1, 96><<<192, 256, 0, stream>>>(x, buf0, W_ih0_1, W_hh_1, b_ih_1,
                                             b_hh_1, 96, 0);
  for (int l = 1; l < 24; ++l) {
    const float* in = (l & 1) ? buf0 : buf1;
    float* outb = (l & 1) ? buf1 : buf0;
    lstm_layer<32, 96><<<192, 256, 0, stream>>>(
        in, outb, W_ih_1 + (size_t)(l - 1) * 4096, W_hh_1 + (size_t)l * 2048,
        b_ih_1 + l * 128, b_hh_1 + l * 128, 3072, 0);
  }
  // ---- stack 2 (N=48; layer0 reads stack1-final with n_off=48) ----
  lstm_layer<32, 48><<<96, 256, 0, stream>>>(buf1, q0, W_ih_2, W_hh_2, b_ih_2,
                                             b_hh_2, 3072, 48);
  for (int l = 1; l < 24; ++l) {
    const float* in = (l & 1) ? q0 : q1;
    float* outb = (l & 1) ? q1 : q0;
    lstm_layer<32, 48><<<96, 256, 0, stream>>>(
        in, outb, W_ih_2 + (size_t)l * 4096, W_hh_2 + (size_t)l * 2048,
        b_ih_2 + l * 128, b_hh_2 + l * 128, 1536, 0);
  }
  // ---- FC head ----
  fc1_kernel<<<dim3(16, 4), 256, 0, stream>>>(q1, buf1, fc1_w, fc1_b, y1);
  fc2_kernel<<<256, 64, 0, stream>>>(y1, fc2_w, fc2_b, (float*)d_out);
}

// Round 5
// 2241.040 us; speedup vs baseline: 2.0469x; 1.1782x over previous
//
#include <hip/hip_runtime.h>

// ---------------------------------------------------------------------------
// Model: x:(256,1,96) -> 24-layer biLSTM (scan over batch axis: N=96 rows are
// independent chains, T=256 steps) -> slice n in [48,96) -> 24-layer biLSTM
// (N=48) -> z=h2+x1 -> fc1(1536->1000,relu) -> fc2(1000->48) -> FP32 out.
//
// Round-5:
//  - phase 1a: coalesced, fully-pipelined global->LDS staging of the x tile
//    into xg[t][32..63] (reuses the xg buffer; in-wave LDS ordering makes the
//    read-then-overwrite in 1b safe). Kills the 64x serialized-latency loop
//    that dominated round 4 (~25 us/layer).
//  - phase 1b: xg[t][r] = bias + Wih.x[t] from LDS broadcast ds_read_b128.
//  - phase 2: wave-0 recurrence, xg prefetch distance 2, manual 2x unroll;
//    h written to the consumed xg row (no global store / exec dance in loop);
//    cooperative coalesced write-out by all 4 waves at the end.
//  - fc1: register double-buffered k-tiles.
// ---------------------------------------------------------------------------

template <int SEL>
__device__ __forceinline__ float quad_bcast(float v) {
  return __int_as_float(__builtin_amdgcn_update_dpp(
      0, __float_as_int(v), SEL * 0x55, 0xF, 0xF, true));
}

// One block (256 threads) per (direction, chain).
// xin index: t*t_stride + (n+n_off)*IN_SZ + k ; xout: (t*N+n)*32 + d*16 + j.
template <int IN_SZ, int N>
__global__ __launch_bounds__(256) void lstm_layer(
    const float* __restrict__ xin, float* __restrict__ xout,
    const float* __restrict__ Wih, const float* __restrict__ Whh,
    const float* __restrict__ bih, const float* __restrict__ bhh,
    int t_stride, int n_off) {
  __shared__ float xg[256 * 64];  // 64 KB: xg[t][0..63]=gates, [32..63] also
                                  // doubles as x-staging then h history.

  const int tid = threadIdx.x;
  const int lane = tid & 63;
  const int w = tid >> 6;
  const int d = blockIdx.x / N;  // 0 fwd, 1 bwd
  const int n = blockIdx.x % N;

  // ---- phase 1: xg[t][r] = bih[r]+bhh[r] + Wih[d*64+r,:] . x[t,n,:] ----
  {
    const int r = lane;
    const float bias = bih[d * 64 + r] + bhh[d * 64 + r];
    if constexpr (IN_SZ == 1) {
      // per-lane x value for t = w*64+lane, broadcast via readlane
      const float xv =
          xin[(size_t)(w * 64 + lane) * t_stride + (n + n_off)];
      const float wih0 = Wih[d * 64 + r];
      const int xvb = __float_as_int(xv);
      for (int ti = 0; ti < 64; ++ti) {
        const float xs = __int_as_float(__builtin_amdgcn_readlane(xvb, ti));
        xg[(w * 64 + ti) * 64 + r] = fmaf(wih0, xs, bias);
      }
    } else {
      // 1a: stage this wave's 64 x-rows into xg[t][32..63], coalesced &
      // fully pipelined (8 independent float4 loads, then 8 LDS writes).
      const int r8 = lane >> 3;  // row-in-group
      const int c = lane & 7;    // 16B chunk
      const float* gbase = xin + (size_t)(n + n_off) * 32 + c * 4;
      float4 v[8];
#pragma unroll
      for (int i = 0; i < 8; ++i) {
        const int t = w * 64 + i * 8 + r8;
        v[i] = *reinterpret_cast<const float4*>(gbase + (size_t)t * t_stride);
      }
#pragma unroll
      for (int i = 0; i < 8; ++i) {
        const int t = w * 64 + i * 8 + r8;
        *reinterpret_cast<float4*>(&xg[t * 64 + 32 + c * 4]) = v[i];
      }
      // per-lane Wih row (independent loads, reused 64x)
      float wih[32];
      const float4* wp =
          reinterpret_cast<const float4*>(Wih + (size_t)(d * 64 + r) * 32);
#pragma unroll
      for (int q = 0; q < 8; ++q) {
        const float4 t4 = wp[q];
        wih[4 * q + 0] = t4.x;
        wih[4 * q + 1] = t4.y;
        wih[4 * q + 2] = t4.z;
        wih[4 * q + 3] = t4.w;
      }
      // 1b: compute. Reads of row t (broadcast b128) precede the write to
      // xg[t][r] (in-wave LDS ordering) -> safe overwrite of staged x.
      for (int ti = 0; ti < 64; ++ti) {
        const int t = w * 64 + ti;
        const float4* xr = reinterpret_cast<const float4*>(&xg[t * 64 + 32]);
        float a0 = bias, a1 = 0.f, a2 = 0.f, a3 = 0.f;
#pragma unroll
        for (int q = 0; q < 8; ++q) {
          const float4 xv = xr[q];
          a0 = fmaf(wih[4 * q + 0], xv.x, a0);
          a1 = fmaf(wih[4 * q + 1], xv.y, a1);
          a2 = fmaf(wih[4 * q + 2], xv.z, a2);
          a3 = fmaf(wih[4 * q + 3], xv.w, a3);
        }
        xg[t * 64 + r] = (a0 + a1) + (a2 + a3);
      }
    }
  }
  __syncthreads();

  // ---- phase 2: recurrence (wave 0 only) ----
  if (w == 0) {
    const int j = lane >> 2;
    const int g = lane & 3;
    const int r = g * 16 + j;

    float whh[16];
#pragma unroll
    for (int k = 0; k < 16; ++k) whh[k] = Whh[(d * 64 + r) * 16 + k];

    // per-lane activation: sigmoid (g!=2) or tanh (g==2)
    const float s_ = (g == 2) ? 2.885390082f : -1.442695041f;
    const float m_ = (g == 2) ? -2.0f : 1.0f;
    const float b_ = (g == 2) ? 1.0f : 0.0f;

    float hs[16];
#pragma unroll
    for (int k = 0; k < 16; ++k) hs[k] = 0.f;
    float c = 0.f;

    const int dt = d ? -1 : 1;
    int t = d ? 255 : 0;
    float cur0 = xg[t * 64 + r];
    float cur1 = xg[(t + dt) * 64 + r];

#define LSTM_STEP(CUR, TT)                                              \
  {                                                                     \
    float a0 = (CUR), a1 = 0.f, a2 = 0.f, a3 = 0.f;                     \
    _Pragma("unroll") for (int k = 0; k < 16; k += 4) {                 \
      a0 = fmaf(whh[k + 0], hs[k + 0], a0);                             \
      a1 = fmaf(whh[k + 1], hs[k + 1], a1);                             \
      a2 = fmaf(whh[k + 2], hs[k + 2], a2);                             \
      a3 = fmaf(whh[k + 3], hs[k + 3], a3);                             \
    }                                                                   \
    const float gv = (a0 + a1) + (a2 + a3);                             \
    const float e = __builtin_amdgcn_exp2f(s_ * gv);                    \
    const float v = fmaf(m_, __builtin_amdgcn_rcpf(1.0f + e), b_);      \
    const float si = quad_bcast<0>(v);                                  \
    const float sf = quad_bcast<1>(v);                                  \
    const float tg = quad_bcast<2>(v);                                  \
    const float so = quad_bcast<3>(v);                                  \
    c = fmaf(sf, c, si * tg);                                           \
    const float e2 = __builtin_amdgcn_exp2f(2.885390082f * c);          \
    const float th = fmaf(-2.0f, __builtin_amdgcn_rcpf(1.0f + e2), 1.0f); \
    const float h = so * th;                                            \
    xg[(TT)*64 + lane] = h; /* conflict-free, row already consumed */   \
    const int hb = __float_as_int(h);                                   \
    _Pragma("unroll") for (int k = 0; k < 16; ++k) hs[k] =              \
        __int_as_float(__builtin_amdgcn_readlane(hb, 4 * k));           \
  }

    for (int tt = 0; tt < 256; tt += 2) {
      const float nx0 = xg[((t + 2 * dt) & 255) * 64 + r];
      LSTM_STEP(cur0, t)
      const float nx1 = xg[((t + 3 * dt) & 255) * 64 + r];
      LSTM_STEP(cur1, t + dt)
      cur0 = nx0;
      cur1 = nx1;
      t += 2 * dt;
    }
#undef LSTM_STEP
  }
  __syncthreads();

  // ---- phase 3: cooperative coalesced write-out (all 4 waves) ----
  // h_j for row t lives at xg[t*64 + 4j] (any quad position).
  {
    const int q4 = tid & 3;   // float4 index within the 16 outputs
    const int tb = tid >> 2;  // 0..63
#pragma unroll
    for (int p = 0; p < 4; ++p) {
      const int t = p * 64 + tb;
      float4 v;
      v.x = xg[t * 64 + 16 * q4 + 0];
      v.y = xg[t * 64 + 16 * q4 + 4];
      v.z = xg[t * 64 + 16 * q4 + 8];
      v.w = xg[t * 64 + 16 * q4 + 12];
      *reinterpret_cast<float4*>(xout + ((size_t)t * N + n) * 32 + d * 16 +
                                 q4 * 4) = v;
    }
  }
}

// fc1: y1[b,m] = relu( sum_k (h2[b,k] + x1[b,k]) * w1[m,k] + b1[m] )
// 64x64 tiles, 256 threads, 4x4 per thread; k-major LDS; register dbuf.
__global__ __launch_bounds__(256) void fc1_kernel(
    const float* __restrict__ h2,   // (256,1536)
    const float* __restrict__ x1b,  // (256,3072); back half is x1
    const float* __restrict__ w1, const float* __restrict__ b1,
    float* __restrict__ y1) {
  __shared__ float Zs[16][68];
  __shared__ float Ws[16][68];
  const int tid = threadIdx.x;
  const int m0 = blockIdx.x * 64;
  const int b0 = blockIdx.y * 64;
  const int rr = tid >> 2;
  const int c4 = (tid & 3) * 4;
  const int tx = tid & 15, ty = tid >> 4;

  float acc[4][4];
#pragma unroll
  for (int i = 0; i < 4; ++i)
#pragma unroll
    for (int jj = 0; jj < 4; ++jj) acc[i][jj] = 0.f;

  const bool wvalid = (m0 + rr) < 1000;
  const float* zr = h2 + (size_t)(b0 + rr) * 1536 + c4;
  const float* zr2 = x1b + (size_t)(b0 + rr) * 3072 + 1536 + c4;
  const float* wr = w1 + (size_t)(m0 + rr) * 1536 + c4;

  float4 za = *reinterpret_cast<const float4*>(zr);
  float4 zb = *reinterpret_cast<const float4*>(zr2);
  float4 wv = wvalid ? *reinterpret_cast<const float4*>(wr)
                     : make_float4(0.f, 0.f, 0.f, 0.f);

  for (int k0 = 0; k0 < 1536; k0 += 16) {
    Zs[c4 + 0][rr] = za.x + zb.x;
    Zs[c4 + 1][rr] = za.y + zb.y;
    Zs[c4 + 2][rr] = za.z + zb.z;
    Zs[c4 + 3][rr] = za.w + zb.w;
    Ws[c4 + 0][rr] = wv.x;
    Ws[c4 + 1][rr] = wv.y;
    Ws[c4 + 2][rr] = wv.z;
    Ws[c4 + 3][rr] = wv.w;
    // prefetch next k-tile while this one is consumed
    if (k0 + 16 < 1536) {
      za = *reinterpret_cast<const float4*>(zr + k0 + 16);
      zb = *reinterpret_cast<const float4*>(zr2 + k0 + 16);
      if (wvalid) wv = *reinterpret_cast<const float4*>(wr + k0 + 16);
    }
    __syncthreads();
#pragma unroll
    for (int kk = 0; kk < 16; ++kk) {
      const float4 av = *reinterpret_cast<const float4*>(&Zs[kk][ty * 4]);
      const float4 bv = *reinterpret_cast<const float4*>(&Ws[kk][tx * 4]);
      const float a_[4] = {av.x, av.y, av.z, av.w};
      const float b_[4] = {bv.x, bv.y, bv.z, bv.w};
#pragma unroll
      for (int i = 0; i < 4; ++i)
#pragma unroll
        for (int jj = 0; jj < 4; ++jj)
          acc[i][jj] = fmaf(a_[i], b_[jj], acc[i][jj]);
    }
    __syncthreads();
  }
#pragma unroll
  for (int i = 0; i < 4; ++i) {
    const int b = b0 + ty * 4 + i;
#pragma unroll
    for (int jj = 0; jj < 4; ++jj) {
      const int m = m0 + tx * 4 + jj;
      if (m < 1000) {
        float vo = acc[i][jj] + b1[m];
        y1[(size_t)b * 1000 + m] = vo > 0.f ? vo : 0.f;
      }
    }
  }
}

// fc2: out[b,p] = sum_m y1[b,m]*w2[p,m] + b2[p], p<48; FP32 store.
__global__ __launch_bounds__(64) void fc2_kernel(
    const float* __restrict__ y1, const float* __restrict__ w2,
    const float* __restrict__ b2, float* __restrict__ out) {
  __shared__ float ys[1000];
  const int b = blockIdx.x;
  for (int k = threadIdx.x; k < 1000; k += 64) ys[k] = y1[(size_t)b * 1000 + k];
  __syncthreads();
  const int p = threadIdx.x;
  if (p < 48) {
    float a0 = b2[p], a1 = 0.f, a2 = 0.f, a3 = 0.f;
    const float* wr = w2 + (size_t)p * 1000;
    for (int k = 0; k < 1000; k += 4) {
      const float4 wv = *reinterpret_cast<const float4*>(wr + k);
      a0 = fmaf(ys[k + 0], wv.x, a0);
      a1 = fmaf(ys[k + 1], wv.y, a1);
      a2 = fmaf(ys[k + 2], wv.z, a2);
      a3 = fmaf(ys[k + 3], wv.w, a3);
    }
    out[(size_t)b * 48 + p] = (a0 + a1) + (a2 + a3);
  }
}

extern "C" void kernel_launch(void* const* d_in, const int* in_sizes, int n_in,
                              void* d_out, int out_size, void* d_ws,
                              size_t ws_size, hipStream_t stream) {
  const float* x = (const float*)d_in[0];
  const float* W_ih0_1 = (const float*)d_in[1];
  const float* W_ih_1 = (const float*)d_in[2];
  const float* W_hh_1 = (const float*)d_in[3];
  const float* b_ih_1 = (const float*)d_in[4];
  const float* b_hh_1 = (const float*)d_in[5];
  const float* W_ih_2 = (const float*)d_in[6];
  const float* W_hh_2 = (const float*)d_in[7];
  const float* b_ih_2 = (const float*)d_in[8];
  const float* b_hh_2 = (const float*)d_in[9];
  const float* fc1_w = (const float*)d_in[10];
  const float* fc1_b = (const float*)d_in[11];
  const float* fc2_w = (const float*)d_in[12];
  const float* fc2_b = (const float*)d_in[13];

  float* ws = (float*)d_ws;
  float* buf0 = ws;             // 786432 floats (256*96*32)
  float* buf1 = ws + 786432;    // stack1 final (x1 source)
  float* y1 = ws + 2 * 786432;  // 256000 floats
  float* q0 = buf0;             // stack2 ping/pong alias buf0 (safe)
  float* q1 = buf0 + 393216;

  // ---- stack 1 (N=96 chains/dir; layer0 in_sz=1, t_stride=96) ----
  lstm_layer<1, 96><<<192, 256, 0, stream>>>(x, buf0, W_ih0_1, W_hh_1, b_ih_1,
                                             b_hh_1, 96, 0);
  for (int l = 1; l < 24; ++l) {
    const float* in = (l & 1) ? buf0 : buf1;
    float* outb = (l & 1) ? buf1 : buf0;
    lstm_layer<32, 96><<<192, 256, 0, stream>>>(
        in, outb, W_ih_1 + (size_t)(l - 1) * 4096, W_hh_1 + (size_t)l * 2048,
        b_ih_1 + l * 128, b_hh_1 + l * 128, 3072, 0);
  }
  // ---- stack 2 (N=48; layer0 reads stack1-final with n_off=48) ----
  lstm_layer<32, 48><<<96, 256, 0, stream>>>(buf1, q0, W_ih_2, W_hh_2, b_ih_2,
                                             b_hh_2, 3072, 48);
  for (int l = 1; l < 24; ++l) {
    const float* in = (l & 1) ? q0 : q1;
    float* outb = (l & 1) ? q1 : q0;
    lstm_layer<32, 48><<<96, 256, 0, stream>>>(
        in, outb, W_ih_2 + (size_t)l * 4096, W_hh_2 + (size_t)l * 2048,
        b_ih_2 + l * 128, b_hh_2 + l * 128, 1536, 0);
  }
  // ---- FC head ----
  fc1_kernel<<<dim3(16, 4), 256, 0, stream>>>(q1, buf1, fc1_w, fc1_b, y1);
  fc2_kernel<<<256, 64, 0, stream>>>(y1, fc2_w, fc2_b, (float*)d_out);
}